// Round 9
// baseline (136.873 us; speedup 1.0000x reference)
//
#include <hip/hip_runtime.h>

#define N_ATOMS 10000
#define N_DIH   8000
#define NB      2048          // frames (innermost, contiguous)
#define EPS     1e-12f

typedef float f4_t __attribute__((ext_vector_type(4)));

// Math BIT-IDENTICAL per (dihedral, frame) to rounds 6/7/8 (all passing,
// absmax 0.0039). Structural change only: software-pipelined register
// double-buffer. Wave w == dihedral w; lane l at iteration i handles
// frame-group fg = i*64 + l (4 frames). Loads for iteration i+1 are issued
// BEFORE the ~1000-cycle compute of iteration i, so the compiler's counted
// vmcnt lets 12 gathers stay in flight under compute (true MLP, which the
// VGPR=32 schedules of R1-R8 never had).
__device__ __forceinline__ void compute_store_unit(
    const f4_t* __restrict__ g,   // g[j*3+c], 4 frames each
    int fg, float* __restrict__ o0base, float* __restrict__ o1base)
{
    f4_t v0, v1;
#pragma unroll
    for (int k = 0; k < 4; ++k) {
        float p[4][3];
#pragma unroll
        for (int j = 0; j < 4; ++j) {
            p[j][0] = g[j * 3 + 0][k];
            p[j][1] = g[j * 3 + 1][k];
            p[j][2] = g[j * 3 + 2][k];
        }

        float a12[3], a23[3], a34[3];
#pragma unroll
        for (int c = 0; c < 3; ++c) {
            a12[c] = p[1][c] - p[0][c];
            a23[c] = p[2][c] - p[1][c];
            a34[c] = p[3][c] - p[2][c];
        }
        // normalize exactly as R1/R6 (IEEE sqrt + IEEE division) — proven
        // sign-critical at near-degenerate dihedrals (R5 bisection).
        {
            float n12 = sqrtf(a12[0]*a12[0] + a12[1]*a12[1] + a12[2]*a12[2]);
            float n23 = sqrtf(a23[0]*a23[0] + a23[1]*a23[1] + a23[2]*a23[2]);
            float n34 = sqrtf(a34[0]*a34[0] + a34[1]*a34[1] + a34[2]*a34[2]);
            float i12 = 1.0f / fmaxf(n12, EPS);
            float i23 = 1.0f / fmaxf(n23, EPS);
            float i34 = 1.0f / fmaxf(n34, EPS);
#pragma unroll
            for (int c = 0; c < 3; ++c) { a12[c] *= i12; a23[c] *= i23; a34[c] *= i34; }
        }

        float vp1[3], vp2[3], vp3[3];
        vp1[0] = a12[1]*a23[2] - a12[2]*a23[1];
        vp1[1] = a12[2]*a23[0] - a12[0]*a23[2];
        vp1[2] = a12[0]*a23[1] - a12[1]*a23[0];

        vp2[0] = a23[1]*a34[2] - a23[2]*a34[1];
        vp2[1] = a23[2]*a34[0] - a23[0]*a34[2];
        vp2[2] = a23[0]*a34[1] - a23[1]*a34[0];

        vp3[0] = vp1[1]*a23[2] - vp1[2]*a23[1];
        vp3[1] = vp1[2]*a23[0] - vp1[0]*a23[2];
        vp3[2] = vp1[0]*a23[1] - vp1[1]*a23[0];

        float sp1 = vp1[0]*vp2[0] + vp1[1]*vp2[1] + vp1[2]*vp2[2];
        float sp2 = vp3[0]*vp2[0] + vp3[1]*vp2[1] + vp3[2]*vp2[2];

        // FINAL normalize: magnitude-only rsq approximation (sign-exact,
        // proven passing since R6).
        float s2  = sp1*sp1 + sp2*sp2;
        float inv = __builtin_amdgcn_rsqf(fmaxf(s2, 1e-24f));
        v0[k] = -sp2 * inv;   // st[0]
        v1[k] =  sp1 * inv;   // st[1]
    }

    *reinterpret_cast<f4_t*>(o0base + (fg << 2)) = v0;
    *reinterpret_cast<f4_t*>(o1base + (fg << 2)) = v1;
}

__global__ __launch_bounds__(256, 3) void dihedral_kernel(
    const float* __restrict__ x,      // (N_ATOMS, 3, NB)
    const int*   __restrict__ atoms,  // (N_DIH, 4)
    float*       __restrict__ out)    // (2*N_DIH, NB)
{
    const int lane = threadIdx.x & 63;
    // wave-uniform dihedral id -> scalar regs (s_load atoms, SGPR row bases)
    const int d = __builtin_amdgcn_readfirstlane(blockIdx.x * 4 + (threadIdx.x >> 6));

    const int4 aidx = *reinterpret_cast<const int4*>(atoms + (size_t)d * 4);
    const float* __restrict__ r0 = x + (size_t)aidx.x * (3 * NB);
    const float* __restrict__ r1 = x + (size_t)aidx.y * (3 * NB);
    const float* __restrict__ r2 = x + (size_t)aidx.z * (3 * NB);
    const float* __restrict__ r3 = x + (size_t)aidx.w * (3 * NB);

    float* __restrict__ o0base = out + (size_t)d * NB;
    float* __restrict__ o1base = out + (size_t)(N_DIH + d) * NB;

    f4_t bufA[12], bufB[12];

#define LOADU(BUF, I) do {                                                   \
        const int fo_ = (((I) * 64 + lane) << 2);                            \
        (BUF)[0]  = *reinterpret_cast<const f4_t*>(r0 + 0 * NB + fo_);       \
        (BUF)[1]  = *reinterpret_cast<const f4_t*>(r0 + 1 * NB + fo_);       \
        (BUF)[2]  = *reinterpret_cast<const f4_t*>(r0 + 2 * NB + fo_);       \
        (BUF)[3]  = *reinterpret_cast<const f4_t*>(r1 + 0 * NB + fo_);       \
        (BUF)[4]  = *reinterpret_cast<const f4_t*>(r1 + 1 * NB + fo_);       \
        (BUF)[5]  = *reinterpret_cast<const f4_t*>(r1 + 2 * NB + fo_);       \
        (BUF)[6]  = *reinterpret_cast<const f4_t*>(r2 + 0 * NB + fo_);       \
        (BUF)[7]  = *reinterpret_cast<const f4_t*>(r2 + 1 * NB + fo_);       \
        (BUF)[8]  = *reinterpret_cast<const f4_t*>(r2 + 2 * NB + fo_);       \
        (BUF)[9]  = *reinterpret_cast<const f4_t*>(r3 + 0 * NB + fo_);       \
        (BUF)[10] = *reinterpret_cast<const f4_t*>(r3 + 1 * NB + fo_);       \
        (BUF)[11] = *reinterpret_cast<const f4_t*>(r3 + 2 * NB + fo_);       \
    } while (0)

    LOADU(bufA, 0);
#pragma unroll
    for (int i = 0; i < 8; ++i) {
        if ((i & 1) == 0) {
            if (i < 7) LOADU(bufB, i + 1);          // issue next-unit loads
            compute_store_unit(bufA, i * 64 + lane, o0base, o1base);
        } else {
            if (i < 7) LOADU(bufA, i + 1);
            compute_store_unit(bufB, i * 64 + lane, o0base, o1base);
        }
    }
#undef LOADU
}

extern "C" void kernel_launch(void* const* d_in, const int* in_sizes, int n_in,
                              void* d_out, int out_size, void* d_ws, size_t ws_size,
                              hipStream_t stream) {
    const float* x     = (const float*)d_in[0];
    const int*   atoms = (const int*)d_in[1];
    float*       out   = (float*)d_out;

    // 2000 blocks x 4 waves = 8000 waves; wave w <-> dihedral w
    dihedral_kernel<<<2000, 256, 0, stream>>>(x, atoms, out);
}